// Round 9
// baseline (39410.132 us; speedup 1.0000x reference)
//
#include <hip/hip_runtime.h>
#include <hip/hip_bf16.h>

static constexpr int Bb = 32;
static constexpr int Tt = 1024;
static constexpr int Ii = 1024;
static constexpr int Hh = 1024;
static constexpr int NWG = 256;

static constexpr int HSLOT = Hh * 16;          // 16384 elems per half-slot (16 batches)
static constexpr int NSLOT2 = 2 * (3 * Tt + 1);

typedef float f4 __attribute__((ext_vector_type(4)));

static constexpr int LDS_WORDS = 36 * 1024 + 2 * 768;   // R (swizzled) + partials A,B
static constexpr int LDS_BYTES = LDS_WORDS * 4;         // 153600

static constexpr unsigned SENT32 = 0x7FC0DEADu;         // f32 NaN payload sentinel
static constexpr unsigned SENT16 = 0x7FC1u;             // bf16 NaN sentinel

template <typename PT> __device__ __forceinline__ float pt_to_f(PT v);
template <> __device__ __forceinline__ float pt_to_f<float>(float v) { return v; }
template <> __device__ __forceinline__ float pt_to_f<__hip_bfloat16>(__hip_bfloat16 v) { return __bfloat162float(v); }

template <typename PT> __device__ __forceinline__ PT f_to_pt(float v);
template <> __device__ __forceinline__ float f_to_pt<float>(float v) { return v; }
template <> __device__ __forceinline__ __hip_bfloat16 f_to_pt<__hip_bfloat16>(float v) { return __float2bfloat16(v); }

// Cached loads: fast path (L2 dedup). Non-sentinel value == final value
// (write-once ring). Bypass loads: retry path, always see L3 truth.
#define CGLD(dst, p, lit) \
    asm volatile("global_load_dwordx4 %0, %1, off offset:" lit : "=v"(dst) : "v"(p))
#define CG4(sv, p, a,b,c,d2) \
    CGLD(sv[0],p,a); CGLD(sv[1],p,b); CGLD(sv[2],p,c); CGLD(sv[3],p,d2)
#define BGLD(dst, p, lit) \
    asm volatile("global_load_dwordx4 %0, %1, off offset:" lit " sc0 sc1" : "=v"(dst) : "v"(p))
#define BG4(sv, p, a,b,c,d2) \
    BGLD(sv[0],p,a); BGLD(sv[1],p,b); BGLD(sv[2],p,c); BGLD(sv[3],p,d2)
#define CGLD2(dst, p, lit) \
    asm volatile("global_load_dwordx2 %0, %1, off offset:" lit : "=v"(dst) : "v"(p))
#define CG4x2(su, p, a,b,c,d2) \
    CGLD2(su[0],p,a); CGLD2(su[1],p,b); CGLD2(su[2],p,c); CGLD2(su[3],p,d2)
#define BGLD2(dst, p, lit) \
    asm volatile("global_load_dwordx2 %0, %1, off offset:" lit " sc0 sc1" : "=v"(dst) : "v"(p))
#define BG4x2(su, p, a,b,c,d2) \
    BGLD2(su[0],p,a); BGLD2(su[1],p,b); BGLD2(su[2],p,c); BGLD2(su[3],p,d2)
#define VWAIT(n) do { asm volatile("s_waitcnt vmcnt(" #n ")" ::: "memory"); \
                      __builtin_amdgcn_sched_barrier(0); } while (0)

__device__ __forceinline__ int grp4_ok32(const f4* sv) {
    int ok = 1;
#pragma unroll
    for (int i = 0; i < 4; ++i)
#pragma unroll
        for (int j = 0; j < 4; ++j)
            ok &= (__float_as_uint(sv[i][j]) != SENT32);
    return ok;
}
__device__ __forceinline__ int grp4_ok16(const uint2* su) {
    int ok = 1;
#pragma unroll
    for (int i = 0; i < 4; ++i) {
        ok &= ((su[i].x & 0xFFFFu) != SENT16) & ((su[i].x >> 16) != SENT16);
        ok &= ((su[i].y & 0xFFFFu) != SENT16) & ((su[i].y >> 16) != SENT16);
    }
    return ok;
}
#define RETRY4(sv, p, a,b,c,d2) \
    { int _tr = 0; \
      while (!__all(grp4_ok32(sv))) { \
          if (_tr++) __builtin_amdgcn_s_sleep(2); \
          BG4(sv, p, a,b,c,d2); \
          VWAIT(0); \
      } }

// ---------------------------------------------------------------------------
// Projection GEMM: P2[g][t][h][b] = (x[b,t,:] @ W_g)[h]
// ---------------------------------------------------------------------------
template <typename PT>
__global__ __launch_bounds__(256, 2) void proj_gemm(
    const float* __restrict__ X, const float* __restrict__ Wh,
    const float* __restrict__ Wt, const float* __restrict__ Wc,
    PT* __restrict__ P2)
{
    __shared__ float smem[4160];
    float* As = smem;
    float* Bs = smem + 1088;

    const int tid = threadIdx.x;
    const int tx = tid & 15, ty = tid >> 4;
    const int col0 = blockIdx.x * 64;
    const int t0 = blockIdx.y * 2;

    float acc[3][4][4];
#pragma unroll
    for (int g = 0; g < 3; ++g)
#pragma unroll
        for (int mm = 0; mm < 4; ++mm)
#pragma unroll
            for (int nn = 0; nn < 4; ++nn) acc[g][mm][nn] = 0.f;

    const int lm = tid >> 2, lk4 = (tid & 3) * 4;
    const float* aptr = X + ((size_t)(lm & 31) * Tt + (t0 + (lm >> 5))) * Ii + lk4;
    const int bk = tid >> 4, bn4 = (tid & 15) * 4;

    for (int k0 = 0; k0 < Ii; k0 += 16) {
        float4 av = *(const float4*)(aptr + k0);
        As[(lk4 + 0) * 68 + lm] = av.x;
        As[(lk4 + 1) * 68 + lm] = av.y;
        As[(lk4 + 2) * 68 + lm] = av.z;
        As[(lk4 + 3) * 68 + lm] = av.w;
        *(float4*)&Bs[0 * 1024 + bk * 64 + bn4] = *(const float4*)(Wh + (size_t)(k0 + bk) * Hh + col0 + bn4);
        *(float4*)&Bs[1 * 1024 + bk * 64 + bn4] = *(const float4*)(Wt + (size_t)(k0 + bk) * Hh + col0 + bn4);
        *(float4*)&Bs[2 * 1024 + bk * 64 + bn4] = *(const float4*)(Wc + (size_t)(k0 + bk) * Hh + col0 + bn4);
        __syncthreads();
#pragma unroll
        for (int k = 0; k < 16; ++k) {
            float4 a = *(const float4*)&As[k * 68 + ty * 4];
            float a_[4] = {a.x, a.y, a.z, a.w};
#pragma unroll
            for (int g = 0; g < 3; ++g) {
                float4 b = *(const float4*)&Bs[g * 1024 + k * 64 + tx * 4];
                float b_[4] = {b.x, b.y, b.z, b.w};
#pragma unroll
                for (int mm = 0; mm < 4; ++mm)
#pragma unroll
                    for (int nn = 0; nn < 4; ++nn)
                        acc[g][mm][nn] += a_[mm] * b_[nn];
            }
        }
        __syncthreads();
    }

    float* E = smem;
    const int b4 = (tid & 7) * 4;
#pragma unroll 1
    for (int g = 0; g < 3; ++g) {
        __syncthreads();
#pragma unroll
        for (int mm = 0; mm < 4; ++mm)
#pragma unroll
            for (int nn = 0; nn < 4; ++nn)
                E[(ty * 4 + mm) * 65 + tx * 4 + nn] = acc[g][mm][nn];
        __syncthreads();
        PT* dst = P2 + (size_t)g * Tt * Hh * Bb;
#pragma unroll
        for (int it = 0; it < 4; ++it) {
            const int line = (tid >> 3) + it * 32;
            const int tt = line >> 6, hh = line & 63;
            const float o0 = E[(tt * 32 + b4 + 0) * 65 + hh];
            const float o1 = E[(tt * 32 + b4 + 1) * 65 + hh];
            const float o2v = E[(tt * 32 + b4 + 2) * 65 + hh];
            const float o3 = E[(tt * 32 + b4 + 3) * 65 + hh];
            PT* d = dst + ((size_t)(t0 + tt) * Hh + col0 + hh) * Bb + b4;
            d[0] = f_to_pt<PT>(o0); d[1] = f_to_pt<PT>(o1);
            d[2] = f_to_pt<PT>(o2v); d[3] = f_to_pt<PT>(o3);
        }
    }
}

// ---------------------------------------------------------------------------
// init: half-slots 0/1 <- s0 ([h][16] per group); rest <- sentinel fill.
// ---------------------------------------------------------------------------
template <typename RT>
__global__ __launch_bounds__(256) void init_ring(const float* __restrict__ s0,
                                                 RT* __restrict__ ring)
{
    const size_t tid = (size_t)blockIdx.x * 256 + threadIdx.x;
    if (tid < (size_t)Bb * Hh) {
        const int b = (int)(tid >> 10), h = (int)(tid & 1023);
        const int grp = b >> 4, bl = b & 15;
        ring[(size_t)grp * HSLOT + h * 16 + bl] = f_to_pt<RT>(s0[tid]);
    }
    const unsigned sw = (sizeof(RT) == 4) ? SENT32 : ((SENT16 << 16) | SENT16);
    const uint4 pat = {sw, sw, sw, sw};
    uint4* base = (uint4*)(ring + 2 * (size_t)HSLOT);
    const size_t n16 = (size_t)(NSLOT2 - 2) * HSLOT * sizeof(RT) / 16;
    const size_t stride = (size_t)gridDim.x * 256;
    for (size_t i = tid; i < n16; i += stride) base[i] = pat;
}

// ---------------------------------------------------------------------------
// out transpose: half-slots ((3t+3)*2 + grp) [h][16] -> out[b][t][h]; sT at T-1.
// ---------------------------------------------------------------------------
template <typename RT>
__global__ __launch_bounds__(256) void out_transpose(
    const RT* __restrict__ ring, float* __restrict__ out, float* __restrict__ sT)
{
    __shared__ float tile[128 * 33];
    const int tid = threadIdx.x;
    const int h0 = blockIdx.x * 128;
    const int t = blockIdx.y;
    const RT* srcA = ring + (size_t)((3 * t + 3) * 2) * HSLOT + h0 * 16;
    const RT* srcB = srcA + HSLOT;
#pragma unroll
    for (int e = 0; e < 16; ++e) {
        const int idx = e * 256 + tid;
        const int h = idx >> 5, b = idx & 31;
        const float v = (b < 16) ? pt_to_f<RT>(srcA[h * 16 + b])
                                 : pt_to_f<RT>(srcB[h * 16 + (b - 16)]);
        tile[h * 33 + b] = v;
    }
    __syncthreads();
    const int hi = tid & 31, bq = tid >> 5;
#pragma unroll
    for (int e = 0; e < 4; ++e) {
        const int b = bq + e * 8;
        float4 v;
        v.x = tile[(hi * 4 + 0) * 33 + b];
        v.y = tile[(hi * 4 + 1) * 33 + b];
        v.z = tile[(hi * 4 + 2) * 33 + b];
        v.w = tile[(hi * 4 + 3) * 33 + b];
        *(float4*)(out + ((size_t)b * Tt + t) * Hh + h0 + hi * 4) = v;
        if (t == Tt - 1) *(float4*)(sT + (size_t)b * Hh + h0 + hi * 4) = v;
    }
}

// ---------------------------------------------------------------------------
// Dual-chain staggered dataflow recurrence (no flags, no barriers).
// Chains A (b0-15) / B (b16-31) on separate write-once half-rings. Per
// phase: loadA->computeA->storeA -> loadB->computeB->storeB. Each chain's
// consume happens ~a half-phase+ of compute after its producers stored ->
// first CACHED try usually valid -> L2 dedup (no sentinel poisoning);
// residual races self-heal via per-group bypass retry (deadlock-free).
// Thread map: ks=tid>>2 (64 K-slices of 16), bq=tid&3 (4 of 16 batches).
// ---------------------------------------------------------------------------
template <typename PT, typename RT>
__global__ __launch_bounds__(256, 1) void rhn_recur(
    const float* __restrict__ Rh, const float* __restrict__ Rt,
    const float* __restrict__ Rc, const float* __restrict__ bh,
    const float* __restrict__ bt, const float* __restrict__ bc,
    const PT* __restrict__ P2, RT* __restrict__ ring)
{
    extern __shared__ float lds[];
    float* partA = lds + 36 * 1024;       // [4 waves][12 jl][16 b]
    float* partB = partA + 768;

    const int g = blockIdx.x;
    const int tid = threadIdx.x;

    {   // load R rows, swizzle word = j*1024 + (k ^ (((k>>5)&3)<<2))
        const int k4 = tid * 4;
        const int sk = k4 ^ (((k4 >> 5) & 3) << 2);
#pragma unroll 1
        for (int j = 0; j < 36; ++j) {
            const int l = j / 12;
            const int rem = j - l * 12;
            const int gt = rem >> 2;
            const int q = rem & 3;
            const int h = (q << 8) | g;
            const float* src = (gt == 0 ? Rh : (gt == 1 ? Rt : Rc)) + ((size_t)l * Hh + h) * Hh;
            *(float4*)&lds[(j << 10) | sk] = *(const float4*)(src + k4);
        }
    }
    __syncthreads();

    const int ks = tid >> 2;              // 0..63 K-slices of 16
    const int bq = tid & 3;
    const int b0 = bq << 2;               // batch quad within 16
    const int wv = tid >> 6;
    const int jsel = ks & 15;
    const int ubb = tid & 15;             // update: batch (tid<64)
    const int uq  = (tid >> 4) & 3;
    const int uhc = (uq << 8) | g;

    int o2[4];
#pragma unroll
    for (int c = 0; c < 4; ++c)
        o2[c] = (((ks << 4) | (c << 2))) ^ ((((ks << 4) >> 5) & 3) << 2);

    float brh[3], brt[3], brc[3];
#pragma unroll
    for (int l = 0; l < 3; ++l) {
        brh[l] = bh[l * Hh + uhc];
        brt[l] = bt[l * Hh + uhc];
        brc[l] = bc[l * Hh + uhc];
    }

    float soA = pt_to_f<RT>(ring[uhc * 16 + ubb]);
    float soB = pt_to_f<RT>(ring[(size_t)HSLOT + uhc * 16 + ubb]);

    const size_t THB = (size_t)Tt * Hh * Bb;
    float pvA0 = 0.f, pvA1 = 0.f, pvA2 = 0.f, pvB0 = 0.f, pvB1 = 0.f, pvB2 = 0.f;
    auto loadP = [&](int tt) {            // P2 prefetch one t ahead (off critical path)
        if (tid < 64) {
            const size_t pb = ((size_t)tt * Hh + uhc) * Bb + ubb;
            pvA0 = pt_to_f<PT>(P2[pb]);
            pvA1 = pt_to_f<PT>(P2[THB + pb]);
            pvA2 = pt_to_f<PT>(P2[2 * THB + pb]);
            pvB0 = pt_to_f<PT>(P2[pb + 16]);
            pvB1 = pt_to_f<PT>(P2[THB + pb + 16]);
            pvB2 = pt_to_f<PT>(P2[2 * THB + pb + 16]);
        }
    };
    loadP(0);

    auto halfstep = [&](const float* rp, const RT* rs, RT* rw, float& so,
                        float pv0, float pv1, float pv2, bool addP,
                        float bb0, float bb1, float bb2, float* part) {
        f4 accv[12];
#pragma unroll
        for (int jj = 0; jj < 12; ++jj) accv[jj] = (f4){0.f, 0.f, 0.f, 0.f};

        if constexpr (sizeof(RT) == 4) {
            const float* sA = (const float*)rs + (size_t)(ks << 4) * 16 + b0;
            f4 sv0[4], sv1[4], sv2[4], sv3[4];
            CG4(sv0, sA, "0","64","128","192");
            CG4(sv1, sA, "256","320","384","448");
            CG4(sv2, sA, "512","576","640","704");
            CG4(sv3, sA, "768","832","896","960");
            VWAIT(12);
            RETRY4(sv0, sA, "0","64","128","192");
#pragma unroll
            for (int jj = 0; jj < 12; ++jj) {
                const f4 r = *(const f4*)(rp + jj * 1024 + o2[0]);
                f4 a = accv[jj];
                a += sv0[0] * r[0]; a += sv0[1] * r[1]; a += sv0[2] * r[2]; a += sv0[3] * r[3];
                accv[jj] = a;
            }
            VWAIT(8);
            RETRY4(sv1, sA, "256","320","384","448");
#pragma unroll
            for (int jj = 0; jj < 12; ++jj) {
                const f4 r = *(const f4*)(rp + jj * 1024 + o2[1]);
                f4 a = accv[jj];
                a += sv1[0] * r[0]; a += sv1[1] * r[1]; a += sv1[2] * r[2]; a += sv1[3] * r[3];
                accv[jj] = a;
            }
            VWAIT(4);
            RETRY4(sv2, sA, "512","576","640","704");
#pragma unroll
            for (int jj = 0; jj < 12; ++jj) {
                const f4 r = *(const f4*)(rp + jj * 1024 + o2[2]);
                f4 a = accv[jj];
                a += sv2[0] * r[0]; a += sv2[1] * r[1]; a += sv2[2] * r[2]; a += sv2[3] * r[3];
                accv[jj] = a;
            }
            VWAIT(0);
            RETRY4(sv3, sA, "768","832","896","960");
#pragma unroll
            for (int jj = 0; jj < 12; ++jj) {
                const f4 r = *(const f4*)(rp + jj * 1024 + o2[3]);
                f4 a = accv[jj];
                a += sv3[0] * r[0]; a += sv3[1] * r[1]; a += sv3[2] * r[2]; a += sv3[3] * r[3];
                accv[jj] = a;
            }
        } else {
            const __hip_bfloat16* sIn = (const __hip_bfloat16*)rs + (size_t)(ks << 4) * 16 + b0;
#pragma unroll 1
            for (int blk = 0; blk < 4; ++blk) {
                uint2 su[4];
                const __hip_bfloat16* pb2 = sIn + (size_t)blk * 64;
                CG4x2(su, pb2, "0","32","64","96");
                VWAIT(0);
                int _tr = 0;
                while (!__all(grp4_ok16(su))) {
                    if (_tr++) __builtin_amdgcn_s_sleep(2);
                    BG4x2(su, pb2, "0","32","64","96");
                    VWAIT(0);
                }
                f4 sv[4];
#pragma unroll
                for (int i = 0; i < 4; ++i) {
                    sv[i][0] = __uint_as_float(su[i].x << 16);
                    sv[i][1] = __uint_as_float(su[i].x & 0xFFFF0000u);
                    sv[i][2] = __uint_as_float(su[i].y << 16);
                    sv[i][3] = __uint_as_float(su[i].y & 0xFFFF0000u);
                }
#pragma unroll
                for (int jj = 0; jj < 12; ++jj) {
                    const f4 r = *(const f4*)(rp + jj * 1024 + o2[blk]);
                    f4 a = accv[jj];
                    a += sv[0] * r[0]; a += sv[1] * r[1]; a += sv[2] * r[2]; a += sv[3] * r[3];
                    accv[jj] = a;
                }
            }
        }

        // butterfly reduce over the 16 ks of this wave (lane bits 2..5)
#pragma unroll
        for (int jj = 0; jj < 12; ++jj) {
#pragma unroll
            for (int st = 4; st <= 32; st <<= 1) {
                accv[jj][0] += __shfl_xor(accv[jj][0], st);
                accv[jj][1] += __shfl_xor(accv[jj][1], st);
                accv[jj][2] += __shfl_xor(accv[jj][2], st);
                accv[jj][3] += __shfl_xor(accv[jj][3], st);
            }
        }
        f4 s1 = accv[0];
#pragma unroll
        for (int j2 = 1; j2 < 12; ++j2) if (jsel == j2) s1 = accv[j2];
        if (jsel < 12) *(f4*)&part[wv * 192 + jsel * 16 + b0] = s1;
        __syncthreads();

        if (tid < 64) {
            float vals[3];
#pragma unroll
            for (int gt = 0; gt < 3; ++gt) {
                const int jl = (gt << 2) + uq;
                vals[gt] = part[jl * 16 + ubb] + part[192 + jl * 16 + ubb]
                         + part[384 + jl * 16 + ubb] + part[576 + jl * 16 + ubb];
            }
            vals[0] += bb0; vals[1] += bb1; vals[2] += bb2;
            if (addP) { vals[0] += pv0; vals[1] += pv1; vals[2] += pv2; }
            const float hv = 1.f - 2.f / (1.f + __expf(2.f * vals[0]));
            const float tv = 1.f / (1.f + __expf(-vals[1]));
            const float cv = 1.f / (1.f + __expf(-vals[2]));
            const float sn = hv * tv + so * cv;
            so = sn;
            RT* wp = rw + uhc * 16 + ubb;
            if constexpr (sizeof(RT) == 4) {
                __hip_atomic_store((float*)wp, sn, __ATOMIC_RELAXED, __HIP_MEMORY_SCOPE_AGENT);
            } else {
                __hip_bfloat16 b16 = __float2bfloat16(sn);
                __hip_atomic_store((unsigned short*)wp, *(unsigned short*)&b16,
                                   __ATOMIC_RELAXED, __HIP_MEMORY_SCOPE_AGENT);
            }
        }
    };

#pragma unroll 1
    for (int t = 0; t < Tt; ++t) {
#pragma unroll 1
        for (int l = 0; l < 3; ++l) {
            const int p = t * 3 + l;
            float bb0, bb1, bb2;
            if (l == 0)      { bb0 = brh[0]; bb1 = brt[0]; bb2 = brc[0]; }
            else if (l == 1) { bb0 = brh[1]; bb1 = brt[1]; bb2 = brc[1]; }
            else             { bb0 = brh[2]; bb1 = brt[2]; bb2 = brc[2]; }
            const float* rp = lds + l * 12288;

            halfstep(rp, ring + (size_t)(p * 2 + 0) * HSLOT,
                         ring + (size_t)((p + 1) * 2 + 0) * HSLOT,
                     soA, pvA0, pvA1, pvA2, l == 0, bb0, bb1, bb2, partA);
            halfstep(rp, ring + (size_t)(p * 2 + 1) * HSLOT,
                         ring + (size_t)((p + 1) * 2 + 1) * HSLOT,
                     soB, pvB0, pvB1, pvB2, l == 0, bb0, bb1, bb2, partB);

            if (l == 1 && t + 1 < Tt) loadP(t + 1);   // prefetch next t's P2
        }
    }
}

// ---------------------------------------------------------------------------
extern "C" void kernel_launch(void* const* d_in, const int* in_sizes, int n_in,
                              void* d_out, int out_size, void* d_ws, size_t ws_size,
                              hipStream_t stream)
{
    (void)in_sizes; (void)n_in; (void)out_size;
    const float* x  = (const float*)d_in[0];
    const float* s0 = (const float*)d_in[1];
    const float* wh = (const float*)d_in[2];
    const float* wt = (const float*)d_in[3];
    const float* wc = (const float*)d_in[4];
    const float* Rh = (const float*)d_in[5];
    const float* Rt = (const float*)d_in[6];
    const float* Rc = (const float*)d_in[7];
    const float* bh = (const float*)d_in[8];
    const float* bt = (const float*)d_in[9];
    const float* bc = (const float*)d_in[10];

    float* out = (float*)d_out;
    float* sT  = out + (size_t)Bb * Tt * Hh;

    const size_t THB  = (size_t)Tt * Hh * Bb;
    const size_t p2f  = 3 * THB * 4, p2h = 3 * THB * 2;
    const size_t ringF = (size_t)NSLOT2 * HSLOT * 4;
    const size_t ringH = (size_t)NSLOT2 * HSLOT * 2;

    char* w = (char*)d_ws;

    if (ws_size >= p2f + ringF) {
        // tier A: fp32 P2, fp32 ring
        float* P2 = (float*)w;
        float* ring = (float*)(w + p2f);
        proj_gemm<float><<<dim3(16, 512), 256, 0, stream>>>(x, wh, wt, wc, P2);
        init_ring<float><<<2048, 256, 0, stream>>>(s0, ring);
        hipFuncSetAttribute(reinterpret_cast<const void*>(rhn_recur<float, float>),
                            hipFuncAttributeMaxDynamicSharedMemorySize, LDS_BYTES);
        void* args[] = {(void*)&Rh, (void*)&Rt, (void*)&Rc, (void*)&bh, (void*)&bt, (void*)&bc,
                        (void*)&P2, (void*)&ring};
        hipLaunchCooperativeKernel(reinterpret_cast<void*>(rhn_recur<float, float>),
                                   dim3(NWG), dim3(256), args, LDS_BYTES, stream);
        out_transpose<float><<<dim3(8, 1024), 256, 0, stream>>>(ring, out, sT);
    } else if (ws_size >= p2h + ringF) {
        // tier B: bf16 P2, fp32 ring
        __hip_bfloat16* P2 = (__hip_bfloat16*)w;
        float* ring = (float*)(w + p2h);
        proj_gemm<__hip_bfloat16><<<dim3(16, 512), 256, 0, stream>>>(x, wh, wt, wc, P2);
        init_ring<float><<<2048, 256, 0, stream>>>(s0, ring);
        hipFuncSetAttribute(reinterpret_cast<const void*>(rhn_recur<__hip_bfloat16, float>),
                            hipFuncAttributeMaxDynamicSharedMemorySize, LDS_BYTES);
        void* args[] = {(void*)&Rh, (void*)&Rt, (void*)&Rc, (void*)&bh, (void*)&bt, (void*)&bc,
                        (void*)&P2, (void*)&ring};
        hipLaunchCooperativeKernel(reinterpret_cast<void*>(rhn_recur<__hip_bfloat16, float>),
                                   dim3(NWG), dim3(256), args, LDS_BYTES, stream);
        out_transpose<float><<<dim3(8, 1024), 256, 0, stream>>>(ring, out, sT);
    } else {
        // tier D: bf16 P2, bf16 ring (precision fallback)
        __hip_bfloat16* P2 = (__hip_bfloat16*)w;
        __hip_bfloat16* ring = (__hip_bfloat16*)(w + p2h);
        proj_gemm<__hip_bfloat16><<<dim3(16, 512), 256, 0, stream>>>(x, wh, wt, wc, P2);
        init_ring<__hip_bfloat16><<<2048, 256, 0, stream>>>(s0, ring);
        hipFuncSetAttribute(reinterpret_cast<const void*>(rhn_recur<__hip_bfloat16, __hip_bfloat16>),
                            hipFuncAttributeMaxDynamicSharedMemorySize, LDS_BYTES);
        void* args[] = {(void*)&Rh, (void*)&Rt, (void*)&Rc, (void*)&bh, (void*)&bt, (void*)&bc,
                        (void*)&P2, (void*)&ring};
        hipLaunchCooperativeKernel(reinterpret_cast<void*>(rhn_recur<__hip_bfloat16, __hip_bfloat16>),
                                   dim3(NWG), dim3(256), args, LDS_BYTES, stream);
        out_transpose<__hip_bfloat16><<<dim3(8, 1024), 256, 0, stream>>>(ring, out, sT);
    }
}

// Round 11
// 36708.517 us; speedup vs baseline: 1.0736x; 1.0736x over previous
//
#include <hip/hip_runtime.h>
#include <hip/hip_bf16.h>

static constexpr int Bb = 32;
static constexpr int Tt = 1024;
static constexpr int Ii = 1024;
static constexpr int Hh = 1024;
static constexpr int NWG = 256;

static constexpr int SLOT_E = Hh * Bb;       // 32768 elements per ring slot
static constexpr int NSLOT  = 3 * Tt + 1;    // 3073 write-once slots

typedef float f4 __attribute__((ext_vector_type(4)));

static constexpr int LDS_WORDS = 36 * 1024 + 2 * 1536;   // R (swizzled) + partials x2
static constexpr int LDS_BYTES = LDS_WORDS * 4;          // 159744 <= 163840

static constexpr unsigned SENT32 = 0x7FC0DEADu;          // f32 NaN payload sentinel
static constexpr unsigned SENT16 = 0x7FC1u;              // bf16 NaN sentinel

template <typename PT> __device__ __forceinline__ float pt_to_f(PT v);
template <> __device__ __forceinline__ float pt_to_f<float>(float v) { return v; }
template <> __device__ __forceinline__ float pt_to_f<__hip_bfloat16>(__hip_bfloat16 v) { return __bfloat162float(v); }

template <typename PT> __device__ __forceinline__ PT f_to_pt(float v);
template <> __device__ __forceinline__ float f_to_pt<float>(float v) { return v; }
template <> __device__ __forceinline__ __hip_bfloat16 f_to_pt<__hip_bfloat16>(float v) { return __float2bfloat16(v); }

// s_sleep needs a CONSTANT immediate -> backoff ladder of constants.
__device__ __forceinline__ void backoff(int it) {
    if (it < 2)      __builtin_amdgcn_s_sleep(1);
    else if (it < 4) __builtin_amdgcn_s_sleep(2);
    else if (it < 8) __builtin_amdgcn_s_sleep(4);
    else             __builtin_amdgcn_s_sleep(8);
}

// Cached loads (L1+L2 allocate): fast path — only executed AFTER the probe
// gate proved the slot valid in L3, so fills are valid and L2 dedups reads.
#define CGLD(dst, p, lit) \
    asm volatile("global_load_dwordx4 %0, %1, off offset:" lit : "=v"(dst) : "v"(p))
#define CG8(sv, p, a,b,c,d2,e,f,g2,h) \
    CGLD(sv[0],p,a); CGLD(sv[1],p,b); CGLD(sv[2],p,c); CGLD(sv[3],p,d2); \
    CGLD(sv[4],p,e); CGLD(sv[5],p,f); CGLD(sv[6],p,g2); CGLD(sv[7],p,h)
// Bypass loads (sc0 sc1, straight from L3): retry path — always sees truth,
// so liveness never depends on cache invalidation.
#define BGLD(dst, p, lit) \
    asm volatile("global_load_dwordx4 %0, %1, off offset:" lit " sc0 sc1" : "=v"(dst) : "v"(p))
#define BG8(sv, p, a,b,c,d2,e,f,g2,h) \
    BGLD(sv[0],p,a); BGLD(sv[1],p,b); BGLD(sv[2],p,c); BGLD(sv[3],p,d2); \
    BGLD(sv[4],p,e); BGLD(sv[5],p,f); BGLD(sv[6],p,g2); BGLD(sv[7],p,h)
#define CGLD2(dst, p, lit) \
    asm volatile("global_load_dwordx2 %0, %1, off offset:" lit : "=v"(dst) : "v"(p))
#define CG8x2(su, p, a,b,c,d2,e,f,g2,h) \
    CGLD2(su[0],p,a); CGLD2(su[1],p,b); CGLD2(su[2],p,c); CGLD2(su[3],p,d2); \
    CGLD2(su[4],p,e); CGLD2(su[5],p,f); CGLD2(su[6],p,g2); CGLD2(su[7],p,h)
#define BGLD2(dst, p, lit) \
    asm volatile("global_load_dwordx2 %0, %1, off offset:" lit " sc0 sc1" : "=v"(dst) : "v"(p))
#define BG8x2(su, p, a,b,c,d2,e,f,g2,h) \
    BGLD2(su[0],p,a); BGLD2(su[1],p,b); BGLD2(su[2],p,c); BGLD2(su[3],p,d2); \
    BGLD2(su[4],p,e); BGLD2(su[5],p,f); BGLD2(su[6],p,g2); BGLD2(su[7],p,h)
#define VWAIT(n) do { asm volatile("s_waitcnt vmcnt(" #n ")" ::: "memory"); \
                      __builtin_amdgcn_sched_barrier(0); } while (0)

__device__ __forceinline__ int grp_ok32(const f4* sv) {
    int ok = 1;
#pragma unroll
    for (int i = 0; i < 8; ++i)
#pragma unroll
        for (int j = 0; j < 4; ++j)
            ok &= (__float_as_uint(sv[i][j]) != SENT32);
    return ok;
}
__device__ __forceinline__ int grp_ok16(const uint2* su) {
    int ok = 1;
#pragma unroll
    for (int i = 0; i < 8; ++i) {
        ok &= ((su[i].x & 0xFFFFu) != SENT16) & ((su[i].x >> 16) != SENT16);
        ok &= ((su[i].y & 0xFFFFu) != SENT16) & ((su[i].y >> 16) != SENT16);
    }
    return ok;
}

// retry a group with bypass loads until sentinel-free (wave-uniform loop);
// rare after the probe gate (only partial-line store-drain races).
#define RETRY32(sv, p, a,b,c,d2,e,f,g2,h) \
    { int _tr = 0; \
      while (!__all(grp_ok32(sv))) { \
          if (_tr) backoff(_tr); \
          ++_tr; \
          BG8(sv, p, a,b,c,d2,e,f,g2,h); \
          VWAIT(0); \
      } }

// ---------------------------------------------------------------------------
// Projection GEMM: P2[g][t][h][b] = (x[b,t,:] @ W_g)[h]   (unchanged)
// ---------------------------------------------------------------------------
template <typename PT>
__global__ __launch_bounds__(256, 2) void proj_gemm(
    const float* __restrict__ X, const float* __restrict__ Wh,
    const float* __restrict__ Wt, const float* __restrict__ Wc,
    PT* __restrict__ P2)
{
    __shared__ float smem[4160];
    float* As = smem;
    float* Bs = smem + 1088;

    const int tid = threadIdx.x;
    const int tx = tid & 15, ty = tid >> 4;
    const int col0 = blockIdx.x * 64;
    const int t0 = blockIdx.y * 2;

    float acc[3][4][4];
#pragma unroll
    for (int g = 0; g < 3; ++g)
#pragma unroll
        for (int mm = 0; mm < 4; ++mm)
#pragma unroll
            for (int nn = 0; nn < 4; ++nn) acc[g][mm][nn] = 0.f;

    const int lm = tid >> 2, lk4 = (tid & 3) * 4;
    const float* aptr = X + ((size_t)(lm & 31) * Tt + (t0 + (lm >> 5))) * Ii + lk4;
    const int bk = tid >> 4, bn4 = (tid & 15) * 4;

    for (int k0 = 0; k0 < Ii; k0 += 16) {
        float4 av = *(const float4*)(aptr + k0);
        As[(lk4 + 0) * 68 + lm] = av.x;
        As[(lk4 + 1) * 68 + lm] = av.y;
        As[(lk4 + 2) * 68 + lm] = av.z;
        As[(lk4 + 3) * 68 + lm] = av.w;
        *(float4*)&Bs[0 * 1024 + bk * 64 + bn4] = *(const float4*)(Wh + (size_t)(k0 + bk) * Hh + col0 + bn4);
        *(float4*)&Bs[1 * 1024 + bk * 64 + bn4] = *(const float4*)(Wt + (size_t)(k0 + bk) * Hh + col0 + bn4);
        *(float4*)&Bs[2 * 1024 + bk * 64 + bn4] = *(const float4*)(Wc + (size_t)(k0 + bk) * Hh + col0 + bn4);
        __syncthreads();
#pragma unroll
        for (int k = 0; k < 16; ++k) {
            float4 a = *(const float4*)&As[k * 68 + ty * 4];
            float a_[4] = {a.x, a.y, a.z, a.w};
#pragma unroll
            for (int g = 0; g < 3; ++g) {
                float4 b = *(const float4*)&Bs[g * 1024 + k * 64 + tx * 4];
                float b_[4] = {b.x, b.y, b.z, b.w};
#pragma unroll
                for (int mm = 0; mm < 4; ++mm)
#pragma unroll
                    for (int nn = 0; nn < 4; ++nn)
                        acc[g][mm][nn] += a_[mm] * b_[nn];
            }
        }
        __syncthreads();
    }

    float* E = smem;
    const int b4 = (tid & 7) * 4;
#pragma unroll 1
    for (int g = 0; g < 3; ++g) {
        __syncthreads();
#pragma unroll
        for (int mm = 0; mm < 4; ++mm)
#pragma unroll
            for (int nn = 0; nn < 4; ++nn)
                E[(ty * 4 + mm) * 65 + tx * 4 + nn] = acc[g][mm][nn];
        __syncthreads();
        PT* dst = P2 + (size_t)g * Tt * Hh * Bb;
#pragma unroll
        for (int it = 0; it < 4; ++it) {
            const int line = (tid >> 3) + it * 32;
            const int tt = line >> 6, hh = line & 63;
            const float o0 = E[(tt * 32 + b4 + 0) * 65 + hh];
            const float o1 = E[(tt * 32 + b4 + 1) * 65 + hh];
            const float o2v = E[(tt * 32 + b4 + 2) * 65 + hh];
            const float o3 = E[(tt * 32 + b4 + 3) * 65 + hh];
            PT* d = dst + ((size_t)(t0 + tt) * Hh + col0 + hh) * Bb + b4;
            d[0] = f_to_pt<PT>(o0); d[1] = f_to_pt<PT>(o1);
            d[2] = f_to_pt<PT>(o2v); d[3] = f_to_pt<PT>(o3);
        }
    }
}

// ---------------------------------------------------------------------------
// init: slot 0 <- s0 transposed [h][b]; slots 1..NSLOT-1 <- sentinel fill.
// ---------------------------------------------------------------------------
template <typename RT>
__global__ __launch_bounds__(256) void init_ring(const float* __restrict__ s0,
                                                 RT* __restrict__ ring)
{
    const size_t tid = (size_t)blockIdx.x * 256 + threadIdx.x;
    if (tid < (size_t)Bb * Hh) {
        const int b = (int)(tid >> 10), h = (int)(tid & 1023);
        ring[h * 32 + b] = f_to_pt<RT>(s0[tid]);
    }
    const unsigned sw = (sizeof(RT) == 4) ? SENT32 : ((SENT16 << 16) | SENT16);
    const uint4 pat = {sw, sw, sw, sw};
    uint4* base = (uint4*)(ring + SLOT_E);
    const size_t n16 = (size_t)(NSLOT - 1) * SLOT_E * sizeof(RT) / 16;
    const size_t stride = (size_t)gridDim.x * 256;
    for (size_t i = tid; i < n16; i += stride) base[i] = pat;
}

// ---------------------------------------------------------------------------
// out transpose: ring slot (3t+3) [h][b] -> out[b][t][h]; t==T-1 also -> sT.
// ---------------------------------------------------------------------------
template <typename RT>
__global__ __launch_bounds__(256) void out_transpose(
    const RT* __restrict__ ring, float* __restrict__ out, float* __restrict__ sT)
{
    __shared__ float tile[128 * 33];
    const int tid = threadIdx.x;
    const int h0 = blockIdx.x * 128;
    const int t = blockIdx.y;
    const RT* src = ring + (size_t)(3 * t + 3) * SLOT_E + h0 * 32;
#pragma unroll
    for (int e = 0; e < 16; ++e) {
        const int idx = e * 256 + tid;
        tile[(idx >> 5) * 33 + (idx & 31)] = pt_to_f<RT>(src[idx]);
    }
    __syncthreads();
    const int hi = tid & 31, bq = tid >> 5;
#pragma unroll
    for (int e = 0; e < 4; ++e) {
        const int b = bq + e * 8;
        float4 v;
        v.x = tile[(hi * 4 + 0) * 33 + b];
        v.y = tile[(hi * 4 + 1) * 33 + b];
        v.z = tile[(hi * 4 + 2) * 33 + b];
        v.w = tile[(hi * 4 + 3) * 33 + b];
        *(float4*)(out + ((size_t)b * Tt + t) * Hh + h0 + hi * 4) = v;
        if (t == Tt - 1) *(float4*)(sT + (size_t)b * Hh + h0 + hi * 4) = v;
    }
}

// ---------------------------------------------------------------------------
// Barrier-free dataflow recurrence with PROBE-GATED cached reads.
// Per phase: each thread bypass-probes ONE DWORD PER 128B LINE of slot p
// (4KB/WG/iter, constant-immediate backoff) until __syncthreads_and proves
// the whole slot valid in L3. Only then run cached bulk reads -> L2 fills
// are valid -> per-XCD dedup (~1MB/phase fabric), no sentinel poisoning, no
// polling storm. Partial-line store-drain races caught by RETRY32 bypass
// fallback (always sees L3 truth -> deadlock-free).
// ---------------------------------------------------------------------------
template <typename PT, typename RT>
__global__ __launch_bounds__(256, 1) void rhn_recur(
    const float* __restrict__ Rh, const float* __restrict__ Rt,
    const float* __restrict__ Rc, const float* __restrict__ bh,
    const float* __restrict__ bt, const float* __restrict__ bc,
    const PT* __restrict__ P2, RT* __restrict__ ring)
{
    extern __shared__ float lds[];

    const int g = blockIdx.x;
    const int tid = threadIdx.x;

    {   // load R rows, swizzle word = j*1024 + (k ^ (((k>>5)&7)<<2))
        const int k4 = tid * 4;
        const int sk = k4 ^ (((k4 >> 5) & 7) << 2);
#pragma unroll 1
        for (int j = 0; j < 36; ++j) {
            const int l = j / 12;
            const int rem = j - l * 12;
            const int gt = rem >> 2;
            const int q = rem & 3;
            const int h = (q << 8) | g;
            const float* src = (gt == 0 ? Rh : (gt == 1 ? Rt : Rc)) + ((size_t)l * Hh + h) * Hh;
            *(float4*)&lds[(j << 10) | sk] = *(const float4*)(src + k4);
        }
    }
    __syncthreads();

    const int ks = tid >> 3;              // 0..31 K-slices of 32
    const int b0 = (tid & 7) << 2;        // batch quad
    const int q8 = ks & 7;
    const int wv = tid >> 6;              // wave id
    const int ub = tid & 31;              // update: batch (tid<128)
    const int uqc = (tid >> 5) & 3;
    const int uhc = (uqc << 8) | g;

    int o2[8];
#pragma unroll
    for (int c = 0; c < 8; ++c) o2[c] = ((c ^ q8) << 2);

    float brh[3], brt[3], brc[3];
#pragma unroll
    for (int l = 0; l < 3; ++l) {
        brh[l] = bh[l * Hh + uhc];
        brt[l] = bt[l * Hh + uhc];
        brc[l] = bc[l * Hh + uhc];
    }

    float so_reg = pt_to_f<RT>(ring[uhc * 32 + ub]);   // slot 0 = s0

#pragma unroll 1
    for (int t = 0; t < Tt; ++t) {
#pragma unroll 1
        for (int l = 0; l < 3; ++l) {
            const int p = t * 3 + l;
            float* part = lds + 36 * 1024 + (p & 1) * 1536;

            // P2 prefetch (issued before the probe gate; completes during it)
            float pv0 = 0.f, pv1 = 0.f, pv2 = 0.f;
            if (l == 0 && tid < 128) {
                const size_t pb = ((size_t)t * Hh + uhc) * Bb + ub;
                pv0 = pt_to_f<PT>(P2[pb]);
                pv1 = pt_to_f<PT>(P2[(size_t)Tt * Hh * Bb + pb]);
                pv2 = pt_to_f<PT>(P2[2 * (size_t)Tt * Hh * Bb + pb]);
            }

            // ---- probe gate: 1 bypass dword per 128B line of slot p ----
            if constexpr (sizeof(RT) == 4) {
                const float* prb = (const float*)ring + (size_t)p * SLOT_E + (size_t)tid * 128;
                int it = 0;
                for (;;) {
                    float q0, q1, q2, q3;
                    asm volatile(
                        "global_load_dword %0, %4, off sc0 sc1\n\t"
                        "global_load_dword %1, %4, off offset:128 sc0 sc1\n\t"
                        "global_load_dword %2, %4, off offset:256 sc0 sc1\n\t"
                        "global_load_dword %3, %4, off offset:384 sc0 sc1\n\t"
                        "s_waitcnt vmcnt(0)"
                        : "=v"(q0), "=v"(q1), "=v"(q2), "=v"(q3)
                        : "v"(prb) : "memory");
                    const int ok = (__float_as_uint(q0) != SENT32) &
                                   (__float_as_uint(q1) != SENT32) &
                                   (__float_as_uint(q2) != SENT32) &
                                   (__float_as_uint(q3) != SENT32);
                    if (__syncthreads_and(ok)) break;
                    backoff(it);
                    ++it;
                }
            } else {
                const __hip_bfloat16* prb = (const __hip_bfloat16*)ring + (size_t)p * SLOT_E + (size_t)tid * 128;
                int it = 0;
                for (;;) {
                    unsigned q0, q1;
                    asm volatile(
                        "global_load_dword %0, %2, off sc0 sc1\n\t"
                        "global_load_dword %1, %2, off offset:128 sc0 sc1\n\t"
                        "s_waitcnt vmcnt(0)"
                        : "=v"(q0), "=v"(q1)
                        : "v"(prb) : "memory");
                    const int ok = (int)(((q0 & 0xFFFFu) != SENT16) & ((q0 >> 16) != SENT16) &
                                         ((q1 & 0xFFFFu) != SENT16) & ((q1 >> 16) != SENT16));
                    if (__syncthreads_and(ok)) break;
                    backoff(it);
                    ++it;
                }
            }

            const float* rp = lds + l * 12288 + (ks << 5);

            f4 accv[12];
#pragma unroll
            for (int jj = 0; jj < 12; ++jj) accv[jj] = (f4){0.f, 0.f, 0.f, 0.f};

            if constexpr (sizeof(RT) == 4) {
                const float* sA = (const float*)ring + (size_t)p * SLOT_E + (ks << 5) * 32 + b0;
                f4 sv0[8], sv1[8];
                CG8(sv0, sA, "0","128","256","384","512","640","768","896");
                CG8(sv1, sA, "1024","1152","1280","1408","1536","1664","1792","1920");
                VWAIT(8);
                RETRY32(sv0, sA, "0","128","256","384","512","640","768","896");
#pragma unroll
                for (int jj = 0; jj < 12; ++jj) {
                    const f4 r0 = *(const f4*)(rp + jj * 1024 + o2[0]);
                    const f4 r1 = *(const f4*)(rp + jj * 1024 + o2[1]);
                    f4 a = accv[jj];
                    a += sv0[0] * r0[0]; a += sv0[1] * r0[1]; a += sv0[2] * r0[2]; a += sv0[3] * r0[3];
                    a += sv0[4] * r1[0]; a += sv0[5] * r1[1]; a += sv0[6] * r1[2]; a += sv0[7] * r1[3];
                    accv[jj] = a;
                }
                CG8(sv0, sA, "2048","2176","2304","2432","2560","2688","2816","2944");
                VWAIT(8);
                RETRY32(sv1, sA, "1024","1152","1280","1408","1536","1664","1792","1920");
#pragma unroll
                for (int jj = 0; jj < 12; ++jj) {
                    const f4 r0 = *(const f4*)(rp + jj * 1024 + o2[2]);
                    const f4 r1 = *(const f4*)(rp + jj * 1024 + o2[3]);
                    f4 a = accv[jj];
                    a += sv1[0] * r0[0]; a += sv1[1] * r0[1]; a += sv1[2] * r0[2]; a += sv1[3] * r0[3];
                    a += sv1[4] * r1[0]; a += sv1[5] * r1[1]; a += sv1[6] * r1[2]; a += sv1[7] * r1[3];
                    accv[jj] = a;
                }
                CG8(sv1, sA, "3072","3200","3328","3456","3584","3712","3840","3968");
                VWAIT(8);
                RETRY32(sv0, sA, "2048","2176","2304","2432","2560","2688","2816","2944");
#pragma unroll
                for (int jj = 0; jj < 12; ++jj) {
                    const f4 r0 = *(const f4*)(rp + jj * 1024 + o2[4]);
                    const f4 r1 = *(const f4*)(rp + jj * 1024 + o2[5]);
                    f4 a = accv[jj];
                    a += sv0[0] * r0[0]; a += sv0[1] * r0[1]; a += sv0[2] * r0[2]; a += sv0[3] * r0[3];
                    a += sv0[4] * r1[0]; a += sv0[5] * r1[1]; a += sv0[6] * r1[2]; a += sv0[7] * r1[3];
                    accv[jj] = a;
                }
                VWAIT(0);
                RETRY32(sv1, sA, "3072","3200","3328","3456","3584","3712","3840","3968");
#pragma unroll
                for (int jj = 0; jj < 12; ++jj) {
                    const f4 r0 = *(const f4*)(rp + jj * 1024 + o2[6]);
                    const f4 r1 = *(const f4*)(rp + jj * 1024 + o2[7]);
                    f4 a = accv[jj];
                    a += sv1[0] * r0[0]; a += sv1[1] * r0[1]; a += sv1[2] * r0[2]; a += sv1[3] * r0[3];
                    a += sv1[4] * r1[0]; a += sv1[5] * r1[1]; a += sv1[6] * r1[2]; a += sv1[7] * r1[3];
                    accv[jj] = a;
                }
            } else {
                // bf16 ring tier: cached bulk reads post-probe, bypass retry
                const __hip_bfloat16* sIn = (const __hip_bfloat16*)ring + (size_t)p * SLOT_E + (ks << 5) * 32 + b0;
#pragma unroll 1
                for (int blk = 0; blk < 4; ++blk) {
                    uint2 su[8];
                    const __hip_bfloat16* pb2 = sIn + (size_t)blk * 256;
                    CG8x2(su, pb2, "0","64","128","192","256","320","384","448");
                    VWAIT(0);
                    int _tr = 0;
                    while (!__all(grp_ok16(su))) {
                        if (_tr) backoff(_tr);
                        ++_tr;
                        BG8x2(su, pb2, "0","64","128","192","256","320","384","448");
                        VWAIT(0);
                    }
                    f4 sv[8];
#pragma unroll
                    for (int i = 0; i < 8; ++i) {
                        sv[i][0] = __uint_as_float(su[i].x << 16);
                        sv[i][1] = __uint_as_float(su[i].x & 0xFFFF0000u);
                        sv[i][2] = __uint_as_float(su[i].y << 16);
                        sv[i][3] = __uint_as_float(su[i].y & 0xFFFF0000u);
                    }
#pragma unroll
                    for (int jj = 0; jj < 12; ++jj) {
                        const f4 r0 = *(const f4*)(rp + jj * 1024 + o2[blk * 2]);
                        const f4 r1 = *(const f4*)(rp + jj * 1024 + o2[blk * 2 + 1]);
                        f4 a = accv[jj];
                        a += sv[0] * r0[0]; a += sv[1] * r0[1]; a += sv[2] * r0[2]; a += sv[3] * r0[3];
                        a += sv[4] * r1[0]; a += sv[5] * r1[1]; a += sv[6] * r1[2]; a += sv[7] * r1[3];
                        accv[jj] = a;
                    }
                }
            }

            // in-wave reduce over the 8 ks of this wave (tid bits 3..5)
#pragma unroll
            for (int jj = 0; jj < 12; ++jj) {
#pragma unroll
                for (int st = 8; st <= 32; st <<= 1) {
                    accv[jj][0] += __shfl_xor(accv[jj][0], st);
                    accv[jj][1] += __shfl_xor(accv[jj][1], st);
                    accv[jj][2] += __shfl_xor(accv[jj][2], st);
                    accv[jj][3] += __shfl_xor(accv[jj][3], st);
                }
            }
            f4 s1 = accv[0];
#pragma unroll
            for (int j2 = 1; j2 < 8; ++j2) if (q8 == j2) s1 = accv[j2];
            f4 s2 = accv[8];
#pragma unroll
            for (int j2 = 1; j2 < 4; ++j2) if (q8 == j2) s2 = accv[8 + j2];
            *(f4*)&part[(wv * 12 + q8) * 32 + b0] = s1;
            if (q8 < 4) *(f4*)&part[(wv * 12 + 8 + q8) * 32 + b0] = s2;
            __syncthreads();

            if (tid < 128) {
                float vals[3];
#pragma unroll
                for (int gt = 0; gt < 3; ++gt) {
                    const int jl = (gt << 2) + uqc;
                    vals[gt] = part[jl * 32 + ub] + part[(12 + jl) * 32 + ub]
                             + part[(24 + jl) * 32 + ub] + part[(36 + jl) * 32 + ub];
                }
                float bb0, bb1, bb2;
                if (l == 0)      { bb0 = brh[0]; bb1 = brt[0]; bb2 = brc[0]; }
                else if (l == 1) { bb0 = brh[1]; bb1 = brt[1]; bb2 = brc[1]; }
                else             { bb0 = brh[2]; bb1 = brt[2]; bb2 = brc[2]; }
                vals[0] += bb0; vals[1] += bb1; vals[2] += bb2;
                if (l == 0) { vals[0] += pv0; vals[1] += pv1; vals[2] += pv2; }
                const float hv = 1.f - 2.f / (1.f + __expf(2.f * vals[0]));
                const float tv = 1.f / (1.f + __expf(-vals[1]));
                const float cv = 1.f / (1.f + __expf(-vals[2]));
                const float sn = hv * tv + so_reg * cv;
                so_reg = sn;
                RT* wp = ring + (size_t)(p + 1) * SLOT_E + uhc * 32 + ub;
                if constexpr (sizeof(RT) == 4) {
                    __hip_atomic_store((float*)wp, sn, __ATOMIC_RELAXED, __HIP_MEMORY_SCOPE_AGENT);
                } else {
                    __hip_bfloat16 b16 = __float2bfloat16(sn);
                    __hip_atomic_store((unsigned short*)wp, *(unsigned short*)&b16,
                                       __ATOMIC_RELAXED, __HIP_MEMORY_SCOPE_AGENT);
                }
            }
            // partials double-buffered by parity; next phase's probe gate +
            // sync gates any wrap-around reuse
        }
    }
}

// ---------------------------------------------------------------------------
extern "C" void kernel_launch(void* const* d_in, const int* in_sizes, int n_in,
                              void* d_out, int out_size, void* d_ws, size_t ws_size,
                              hipStream_t stream)
{
    (void)in_sizes; (void)n_in; (void)out_size;
    const float* x  = (const float*)d_in[0];
    const float* s0 = (const float*)d_in[1];
    const float* wh = (const float*)d_in[2];
    const float* wt = (const float*)d_in[3];
    const float* wc = (const float*)d_in[4];
    const float* Rh = (const float*)d_in[5];
    const float* Rt = (const float*)d_in[6];
    const float* Rc = (const float*)d_in[7];
    const float* bh = (const float*)d_in[8];
    const float* bt = (const float*)d_in[9];
    const float* bc = (const float*)d_in[10];

    float* out = (float*)d_out;
    float* sT  = out + (size_t)Bb * Tt * Hh;

    const size_t THB  = (size_t)Tt * Hh * Bb;
    const size_t p2f  = 3 * THB * 4, p2h = 3 * THB * 2;
    const size_t ringF = (size_t)NSLOT * SLOT_E * 4;
    const size_t ringH = (size_t)NSLOT * SLOT_E * 2;

    char* w = (char*)d_ws;

    if (ws_size >= p2f + ringF) {
        // tier A: fp32 P2, fp32 ring
        float* P2 = (float*)w;
        float* ring = (float*)(w + p2f);
        proj_gemm<float><<<dim3(16, 512), 256, 0, stream>>>(x, wh, wt, wc, P2);
        init_ring<float><<<2048, 256, 0, stream>>>(s0, ring);
        (void)hipFuncSetAttribute(reinterpret_cast<const void*>(rhn_recur<float, float>),
                                  hipFuncAttributeMaxDynamicSharedMemorySize, LDS_BYTES);
        void* args[] = {(void*)&Rh, (void*)&Rt, (void*)&Rc, (void*)&bh, (void*)&bt, (void*)&bc,
                        (void*)&P2, (void*)&ring};
        (void)hipLaunchCooperativeKernel(reinterpret_cast<void*>(rhn_recur<float, float>),
                                         dim3(NWG), dim3(256), args, LDS_BYTES, stream);
        out_transpose<float><<<dim3(8, 1024), 256, 0, stream>>>(ring, out, sT);
    } else if (ws_size >= p2h + ringF) {
        // tier B: bf16 P2, fp32 ring
        __hip_bfloat16* P2 = (__hip_bfloat16*)w;
        float* ring = (float*)(w + p2h);
        proj_gemm<__hip_bfloat16><<<dim3(16, 512), 256, 0, stream>>>(x, wh, wt, wc, P2);
        init_ring<float><<<2048, 256, 0, stream>>>(s0, ring);
        (void)hipFuncSetAttribute(reinterpret_cast<const void*>(rhn_recur<__hip_bfloat16, float>),
                                  hipFuncAttributeMaxDynamicSharedMemorySize, LDS_BYTES);
        void* args[] = {(void*)&Rh, (void*)&Rt, (void*)&Rc, (void*)&bh, (void*)&bt, (void*)&bc,
                        (void*)&P2, (void*)&ring};
        (void)hipLaunchCooperativeKernel(reinterpret_cast<void*>(rhn_recur<__hip_bfloat16, float>),
                                         dim3(NWG), dim3(256), args, LDS_BYTES, stream);
        out_transpose<float><<<dim3(8, 1024), 256, 0, stream>>>(ring, out, sT);
    } else {
        // tier D: bf16 P2, bf16 ring (precision fallback)
        __hip_bfloat16* P2 = (__hip_bfloat16*)w;
        __hip_bfloat16* ring = (__hip_bfloat16*)(w + p2h);
        proj_gemm<__hip_bfloat16><<<dim3(16, 512), 256, 0, stream>>>(x, wh, wt, wc, P2);
        init_ring<__hip_bfloat16><<<2048, 256, 0, stream>>>(s0, ring);
        (void)hipFuncSetAttribute(reinterpret_cast<const void*>(rhn_recur<__hip_bfloat16, __hip_bfloat16>),
                                  hipFuncAttributeMaxDynamicSharedMemorySize, LDS_BYTES);
        void* args[] = {(void*)&Rh, (void*)&Rt, (void*)&Rc, (void*)&bh, (void*)&bt, (void*)&bc,
                        (void*)&P2, (void*)&ring};
        (void)hipLaunchCooperativeKernel(reinterpret_cast<void*>(rhn_recur<__hip_bfloat16, __hip_bfloat16>),
                                         dim3(NWG), dim3(256), args, LDS_BYTES, stream);
        out_transpose<__hip_bfloat16><<<dim3(8, 1024), 256, 0, stream>>>(ring, out, sT);
    }
}

// Round 15
// 32542.935 us; speedup vs baseline: 1.2110x; 1.1280x over previous
//
#include <hip/hip_runtime.h>
#include <hip/hip_bf16.h>

static constexpr int Bb = 32;
static constexpr int Tt = 1024;
static constexpr int Ii = 1024;
static constexpr int Hh = 1024;
static constexpr int NWG = 256;

static constexpr int SLOT_E = Hh * Bb;       // 32768 floats per slot (128 KB)
static constexpr int NS     = 16;            // reused slots: 2 MB, L3-resident

typedef float f4 __attribute__((ext_vector_type(4)));

static constexpr int LDS_WORDS = 36 * 1024 + 2 * 1536;   // R (swizzled) + partials x2
static constexpr int LDS_BYTES = LDS_WORDS * 4;          // 159744 <= 163840

template <typename PT> __device__ __forceinline__ float pt_to_f(PT v);
template <> __device__ __forceinline__ float pt_to_f<float>(float v) { return v; }
template <> __device__ __forceinline__ float pt_to_f<__hip_bfloat16>(__hip_bfloat16 v) { return __bfloat162float(v); }

template <typename PT> __device__ __forceinline__ PT f_to_pt(float v);
template <> __device__ __forceinline__ float f_to_pt<float>(float v) { return v; }
template <> __device__ __forceinline__ __hip_bfloat16 f_to_pt<__hip_bfloat16>(float v) { return __float2bfloat16(v); }

// s_sleep needs a CONSTANT immediate -> backoff ladder of constants.
__device__ __forceinline__ void backoff(int it) {
    if (it < 2)      __builtin_amdgcn_s_sleep(1);
    else if (it < 4) __builtin_amdgcn_s_sleep(2);
    else if (it < 8) __builtin_amdgcn_s_sleep(4);
    else             __builtin_amdgcn_s_sleep(8);
}

// Bypass loads (sc0 sc1): straight from L3, the coherence point of the
// producers' write-through stores. Epoch-tag polling self-synchronizes.
#define BGLD(dst, p, lit) \
    asm volatile("global_load_dwordx4 %0, %1, off offset:" lit " sc0 sc1" : "=v"(dst) : "v"(p))
#define BG8(sv, p, a,b,c,d2,e,f,g2,h) \
    BGLD(sv[0],p,a); BGLD(sv[1],p,b); BGLD(sv[2],p,c); BGLD(sv[3],p,d2); \
    BGLD(sv[4],p,e); BGLD(sv[5],p,f); BGLD(sv[6],p,g2); BGLD(sv[7],p,h)
#define VWAIT(n) do { asm volatile("s_waitcnt vmcnt(" #n ")" ::: "memory"); \
                      __builtin_amdgcn_sched_barrier(0); } while (0)

// 2-bit epoch tag in the mantissa LSBs (<=3 ulp perturbation).
// Valid for phase p iff (bits & 3) == (p>>4)&3. Init pattern uses tag 3,
// which no consumer expects until every slot has been rewritten 3 times;
// pre-init ws poison (tag 2) is overwritten by init before recur starts.
__device__ __forceinline__ int grp_tag32(const f4* sv, unsigned texp) {
    int ok = 1;
#pragma unroll
    for (int i = 0; i < 8; ++i)
#pragma unroll
        for (int j = 0; j < 4; ++j)
            ok &= (int)((__float_as_uint(sv[i][j]) & 3u) == texp);
    return ok;
}

#define RETRY32T(sv, texp, p, a,b,c,d2,e,f,g2,h) \
    { int _it = 0; \
      while (!__all(grp_tag32(sv, texp))) { \
          if (_it) backoff(_it); \
          ++_it; \
          BG8(sv, p, a,b,c,d2,e,f,g2,h); \
          VWAIT(0); \
      } }

// ---------------------------------------------------------------------------
// Projection GEMM: P2[g][t][h][b] = (x[b,t,:] @ W_g)[h]   (unchanged)
// ---------------------------------------------------------------------------
template <typename PT>
__global__ __launch_bounds__(256, 2) void proj_gemm(
    const float* __restrict__ X, const float* __restrict__ Wh,
    const float* __restrict__ Wt, const float* __restrict__ Wc,
    PT* __restrict__ P2)
{
    __shared__ float smem[4160];
    float* As = smem;
    float* Bs = smem + 1088;

    const int tid = threadIdx.x;
    const int tx = tid & 15, ty = tid >> 4;
    const int col0 = blockIdx.x * 64;
    const int t0 = blockIdx.y * 2;

    float acc[3][4][4];
#pragma unroll
    for (int g = 0; g < 3; ++g)
#pragma unroll
        for (int mm = 0; mm < 4; ++mm)
#pragma unroll
            for (int nn = 0; nn < 4; ++nn) acc[g][mm][nn] = 0.f;

    const int lm = tid >> 2, lk4 = (tid & 3) * 4;
    const float* aptr = X + ((size_t)(lm & 31) * Tt + (t0 + (lm >> 5))) * Ii + lk4;
    const int bk = tid >> 4, bn4 = (tid & 15) * 4;

    for (int k0 = 0; k0 < Ii; k0 += 16) {
        float4 av = *(const float4*)(aptr + k0);
        As[(lk4 + 0) * 68 + lm] = av.x;
        As[(lk4 + 1) * 68 + lm] = av.y;
        As[(lk4 + 2) * 68 + lm] = av.z;
        As[(lk4 + 3) * 68 + lm] = av.w;
        *(float4*)&Bs[0 * 1024 + bk * 64 + bn4] = *(const float4*)(Wh + (size_t)(k0 + bk) * Hh + col0 + bn4);
        *(float4*)&Bs[1 * 1024 + bk * 64 + bn4] = *(const float4*)(Wt + (size_t)(k0 + bk) * Hh + col0 + bn4);
        *(float4*)&Bs[2 * 1024 + bk * 64 + bn4] = *(const float4*)(Wc + (size_t)(k0 + bk) * Hh + col0 + bn4);
        __syncthreads();
#pragma unroll
        for (int k = 0; k < 16; ++k) {
            float4 a = *(const float4*)&As[k * 68 + ty * 4];
            float a_[4] = {a.x, a.y, a.z, a.w};
#pragma unroll
            for (int g = 0; g < 3; ++g) {
                float4 b = *(const float4*)&Bs[g * 1024 + k * 64 + tx * 4];
                float b_[4] = {b.x, b.y, b.z, b.w};
#pragma unroll
                for (int mm = 0; mm < 4; ++mm)
#pragma unroll
                    for (int nn = 0; nn < 4; ++nn)
                        acc[g][mm][nn] += a_[mm] * b_[nn];
            }
        }
        __syncthreads();
    }

    float* E = smem;
    const int b4 = (tid & 7) * 4;
#pragma unroll 1
    for (int g = 0; g < 3; ++g) {
        __syncthreads();
#pragma unroll
        for (int mm = 0; mm < 4; ++mm)
#pragma unroll
            for (int nn = 0; nn < 4; ++nn)
                E[(ty * 4 + mm) * 65 + tx * 4 + nn] = acc[g][mm][nn];
        __syncthreads();
        PT* dst = P2 + (size_t)g * Tt * Hh * Bb;
#pragma unroll
        for (int it = 0; it < 4; ++it) {
            const int line = (tid >> 3) + it * 32;
            const int tt = line >> 6, hh = line & 63;
            const float o0 = E[(tt * 32 + b4 + 0) * 65 + hh];
            const float o1 = E[(tt * 32 + b4 + 1) * 65 + hh];
            const float o2v = E[(tt * 32 + b4 + 2) * 65 + hh];
            const float o3 = E[(tt * 32 + b4 + 3) * 65 + hh];
            PT* d = dst + ((size_t)(t0 + tt) * Hh + col0 + hh) * Bb + b4;
            d[0] = f_to_pt<PT>(o0); d[1] = f_to_pt<PT>(o1);
            d[2] = f_to_pt<PT>(o2v); d[3] = f_to_pt<PT>(o3);
        }
    }
}

// ---------------------------------------------------------------------------
// init: slot 0 <- s0 transposed [h][b] with 2 LSBs cleared (tag 0);
// slots 1..NS-1 <- 0x00000003 pattern (tag 3). Runs every launch.
// ---------------------------------------------------------------------------
__global__ __launch_bounds__(256) void init_ring_s(const float* __restrict__ s0,
                                                   float* __restrict__ ring)
{
    const size_t tid = (size_t)blockIdx.x * 256 + threadIdx.x;
    if (tid < (size_t)Bb * Hh) {
        const int b = (int)(tid >> 10), h = (int)(tid & 1023);
        ring[h * 32 + b] = __uint_as_float(__float_as_uint(s0[tid]) & ~3u);
    }
    const uint4 pat = {3u, 3u, 3u, 3u};
    uint4* base = (uint4*)(ring + SLOT_E);
    const size_t n16 = (size_t)(NS - 1) * SLOT_E * 4 / 16;
    const size_t stride = (size_t)gridDim.x * 256;
    for (size_t i = tid; i < n16; i += stride) base[i] = pat;
}

// ---------------------------------------------------------------------------
// out transpose from fp32 shist [t][h][b] -> out[b][t][h]; t==T-1 also -> sT.
// ---------------------------------------------------------------------------
__global__ __launch_bounds__(256) void out_transpose_hist(
    const float* __restrict__ shist, float* __restrict__ out, float* __restrict__ sT)
{
    __shared__ float tile[128 * 33];
    const int tid = threadIdx.x;
    const int h0 = blockIdx.x * 128;
    const int t = blockIdx.y;
    const float* src = shist + ((size_t)t * Hh + h0) * Bb;
#pragma unroll
    for (int e = 0; e < 16; ++e) {
        const int idx = e * 256 + tid;
        tile[(idx >> 5) * 33 + (idx & 31)] = src[idx];
    }
    __syncthreads();
    const int hi = tid & 31, bq = tid >> 5;
#pragma unroll
    for (int e = 0; e < 4; ++e) {
        const int b = bq + e * 8;
        float4 v;
        v.x = tile[(hi * 4 + 0) * 33 + b];
        v.y = tile[(hi * 4 + 1) * 33 + b];
        v.z = tile[(hi * 4 + 2) * 33 + b];
        v.w = tile[(hi * 4 + 3) * 33 + b];
        *(float4*)(out + ((size_t)b * Tt + t) * Hh + h0 + hi * 4) = v;
        if (t == Tt - 1) *(float4*)(sT + (size_t)b * Hh + h0 + hi * 4) = v;
    }
}

// ---------------------------------------------------------------------------
// Barrier-free dataflow recurrence on a SMALL REUSED L3-HOT ring (2 MB).
// Phase p reads slot p%NS expecting 2-LSB tag == (p>>4)&3; producers store
// phase p+1 into slot (p+1)%NS with tag ((p+1)>>4)&3. Stale data (skew <= 2
// phases) and the init pattern never match the expected tag -> retried via
// bypass loads (L3 truth -> deadlock-free). Overwrite of slot s (at phase
// s+15) requires ALL WGs past phase s+14 -> no reader can still need it.
// Needs no grid.sync / cooperative features — co-residency only for liveness,
// which a 256-block/256-CU plain launch also provides.
// ---------------------------------------------------------------------------
template <typename PT>
__global__ __launch_bounds__(256, 1) void rhn_recur(
    const float* __restrict__ Rh, const float* __restrict__ Rt,
    const float* __restrict__ Rc, const float* __restrict__ bh,
    const float* __restrict__ bt, const float* __restrict__ bc,
    const PT* __restrict__ P2, float* __restrict__ ring,
    float* __restrict__ shist, const float* __restrict__ s0in)
{
    extern __shared__ float lds[];

    const int g = blockIdx.x;
    const int tid = threadIdx.x;

    {   // load R rows, swizzle word = j*1024 + (k ^ (((k>>5)&7)<<2))
        const int k4 = tid * 4;
        const int sk = k4 ^ (((k4 >> 5) & 7) << 2);
#pragma unroll 1
        for (int j = 0; j < 36; ++j) {
            const int l = j / 12;
            const int rem = j - l * 12;
            const int gt = rem >> 2;
            const int q = rem & 3;
            const int h = (q << 8) | g;
            const float* src = (gt == 0 ? Rh : (gt == 1 ? Rt : Rc)) + ((size_t)l * Hh + h) * Hh;
            *(float4*)&lds[(j << 10) | sk] = *(const float4*)(src + k4);
        }
    }
    __syncthreads();

    const int ks = tid >> 3;              // 0..31 K-slices of 32
    const int b0 = (tid & 7) << 2;        // batch quad
    const int q8 = ks & 7;
    const int wv = tid >> 6;              // wave id
    const int ub = tid & 31;              // update: batch (tid<128)
    const int uqc = (tid >> 5) & 3;
    const int uhc = (uqc << 8) | g;

    int o2[8];
#pragma unroll
    for (int c = 0; c < 8; ++c) o2[c] = ((c ^ q8) << 2);

    float brh[3], brt[3], brc[3];
#pragma unroll
    for (int l = 0; l < 3; ++l) {
        brh[l] = bh[l * Hh + uhc];
        brt[l] = bt[l * Hh + uhc];
        brc[l] = bc[l * Hh + uhc];
    }

    float so_reg = (tid < 128) ? s0in[(size_t)ub * Hh + uhc] : 0.f;

#pragma unroll 1
    for (int t = 0; t < Tt; ++t) {
#pragma unroll 1
        for (int l = 0; l < 3; ++l) {
            const int p = t * 3 + l;
            const int slr = p & (NS - 1);
            const unsigned texp = (unsigned)((p >> 4) & 3);
            const int slw = (p + 1) & (NS - 1);
            const unsigned twr = (unsigned)(((p + 1) >> 4) & 3);
            float* part = lds + 36 * 1024 + (p & 1) * 1536;

            float pv0 = 0.f, pv1 = 0.f, pv2 = 0.f;
            if (l == 0 && tid < 128) {
                const size_t pb = ((size_t)t * Hh + uhc) * Bb + ub;
                pv0 = pt_to_f<PT>(P2[pb]);
                pv1 = pt_to_f<PT>(P2[(size_t)Tt * Hh * Bb + pb]);
                pv2 = pt_to_f<PT>(P2[2 * (size_t)Tt * Hh * Bb + pb]);
            }

            const float* rp = lds + l * 12288 + (ks << 5);

            f4 accv[12];
#pragma unroll
            for (int jj = 0; jj < 12; ++jj) accv[jj] = (f4){0.f, 0.f, 0.f, 0.f};

            const float* sA = ring + (size_t)slr * SLOT_E + (ks << 5) * 32 + b0;
            f4 sv0[8], sv1[8];
            BG8(sv0, sA, "0","128","256","384","512","640","768","896");
            BG8(sv1, sA, "1024","1152","1280","1408","1536","1664","1792","1920");
            VWAIT(8);
            RETRY32T(sv0, texp, sA, "0","128","256","384","512","640","768","896");
#pragma unroll
            for (int jj = 0; jj < 12; ++jj) {
                const f4 r0 = *(const f4*)(rp + jj * 1024 + o2[0]);
                const f4 r1 = *(const f4*)(rp + jj * 1024 + o2[1]);
                f4 a = accv[jj];
                a += sv0[0] * r0[0]; a += sv0[1] * r0[1]; a += sv0[2] * r0[2]; a += sv0[3] * r0[3];
                a += sv0[4] * r1[0]; a += sv0[5] * r1[1]; a += sv0[6] * r1[2]; a += sv0[7] * r1[3];
                accv[jj] = a;
            }
            BG8(sv0, sA, "2048","2176","2304","2432","2560","2688","2816","2944");
            VWAIT(8);
            RETRY32T(sv1, texp, sA, "1024","1152","1280","1408","1536","1664","1792","1920");
#pragma unroll
            for (int jj = 0; jj < 12; ++jj) {
                const f4 r0 = *(const f4*)(rp + jj * 1024 + o2[2]);
                const f4 r1 = *(const f4*)(rp + jj * 1024 + o2[3]);
                f4 a = accv[jj];
                a += sv1[0] * r0[0]; a += sv1[1] * r0[1]; a += sv1[2] * r0[2]; a += sv1[3] * r0[3];
                a += sv1[4] * r1[0]; a += sv1[5] * r1[1]; a += sv1[6] * r1[2]; a += sv1[7] * r1[3];
                accv[jj] = a;
            }
            BG8(sv1, sA, "3072","3200","3328","3456","3584","3712","3840","3968");
            VWAIT(8);
            RETRY32T(sv0, texp, sA, "2048","2176","2304","2432","2560","2688","2816","2944");
#pragma unroll
            for (int jj = 0; jj < 12; ++jj) {
                const f4 r0 = *(const f4*)(rp + jj * 1024 + o2[4]);
                const f4 r1 = *(const f4*)(rp + jj * 1024 + o2[5]);
                f4 a = accv[jj];
                a += sv0[0] * r0[0]; a += sv0[1] * r0[1]; a += sv0[2] * r0[2]; a += sv0[3] * r0[3];
                a += sv0[4] * r1[0]; a += sv0[5] * r1[1]; a += sv0[6] * r1[2]; a += sv0[7] * r1[3];
                accv[jj] = a;
            }
            VWAIT(0);
            RETRY32T(sv1, texp, sA, "3072","3200","3328","3456","3584","3712","3840","3968");
#pragma unroll
            for (int jj = 0; jj < 12; ++jj) {
                const f4 r0 = *(const f4*)(rp + jj * 1024 + o2[6]);
                const f4 r1 = *(const f4*)(rp + jj * 1024 + o2[7]);
                f4 a = accv[jj];
                a += sv1[0] * r0[0]; a += sv1[1] * r0[1]; a += sv1[2] * r0[2]; a += sv1[3] * r0[3];
                a += sv1[4] * r1[0]; a += sv1[5] * r1[1]; a += sv1[6] * r1[2]; a += sv1[7] * r1[3];
                accv[jj] = a;
            }

            // in-wave reduce over the 8 ks of this wave (tid bits 3..5)
#pragma unroll
            for (int jj = 0; jj < 12; ++jj) {
#pragma unroll
                for (int st = 8; st <= 32; st <<= 1) {
                    accv[jj][0] += __shfl_xor(accv[jj][0], st);
                    accv[jj][1] += __shfl_xor(accv[jj][1], st);
                    accv[jj][2] += __shfl_xor(accv[jj][2], st);
                    accv[jj][3] += __shfl_xor(accv[jj][3], st);
                }
            }
            f4 s1 = accv[0];
#pragma unroll
            for (int j2 = 1; j2 < 8; ++j2) if (q8 == j2) s1 = accv[j2];
            f4 s2 = accv[8];
#pragma unroll
            for (int j2 = 1; j2 < 4; ++j2) if (q8 == j2) s2 = accv[8 + j2];
            *(f4*)&part[(wv * 12 + q8) * 32 + b0] = s1;
            if (q8 < 4) *(f4*)&part[(wv * 12 + 8 + q8) * 32 + b0] = s2;
            __syncthreads();

            if (tid < 128) {
                float vals[3];
#pragma unroll
                for (int gt = 0; gt < 3; ++gt) {
                    const int jl = (gt << 2) + uqc;
                    vals[gt] = part[jl * 32 + ub] + part[(12 + jl) * 32 + ub]
                             + part[(24 + jl) * 32 + ub] + part[(36 + jl) * 32 + ub];
                }
                float bb0, bb1, bb2;
                if (l == 0)      { bb0 = brh[0]; bb1 = brt[0]; bb2 = brc[0]; }
                else if (l == 1) { bb0 = brh[1]; bb1 = brt[1]; bb2 = brc[1]; }
                else             { bb0 = brh[2]; bb1 = brt[2]; bb2 = brc[2]; }
                vals[0] += bb0; vals[1] += bb1; vals[2] += bb2;
                if (l == 0) { vals[0] += pv0; vals[1] += pv1; vals[2] += pv2; }
                const float hv = 1.f - 2.f / (1.f + __expf(2.f * vals[0]));
                const float tv = 1.f / (1.f + __expf(-vals[1]));
                const float cv = 1.f / (1.f + __expf(-vals[2]));
                const float sn = hv * tv + so_reg * cv;
                so_reg = sn;
                const unsigned bits = (__float_as_uint(sn) & ~3u) | twr;
                __hip_atomic_store((unsigned*)(ring + (size_t)slw * SLOT_E + uhc * 32 + ub),
                                   bits, __ATOMIC_RELAXED, __HIP_MEMORY_SCOPE_AGENT);
                if (l == 2)
                    shist[((size_t)t * Hh + uhc) * Bb + ub] = sn;
            }
        }
    }
}

// ---------------------------------------------------------------------------
template <typename PT>
static void launch_recur(const float* Rh, const float* Rt, const float* Rc,
                         const float* bh, const float* bt, const float* bc,
                         const PT* P2, float* ring, float* shist,
                         const float* s0, hipStream_t stream)
{
    (void)hipFuncSetAttribute(reinterpret_cast<const void*>(rhn_recur<PT>),
                              hipFuncAttributeMaxDynamicSharedMemorySize, LDS_BYTES);
    void* args[] = {(void*)&Rh, (void*)&Rt, (void*)&Rc, (void*)&bh, (void*)&bt, (void*)&bc,
                    (void*)&P2, (void*)&ring, (void*)&shist, (void*)&s0};
    hipError_t e = hipLaunchCooperativeKernel(reinterpret_cast<void*>(rhn_recur<PT>),
                                              dim3(NWG), dim3(256), args, LDS_BYTES, stream);
    if (e != hipSuccess) {
        // Fallback: plain launch. 256 blocks x 1/CU on 256 CUs -> co-resident.
        rhn_recur<PT><<<dim3(NWG), dim3(256), LDS_BYTES, stream>>>(
            Rh, Rt, Rc, bh, bt, bc, P2, ring, shist, s0);
    }
}

extern "C" void kernel_launch(void* const* d_in, const int* in_sizes, int n_in,
                              void* d_out, int out_size, void* d_ws, size_t ws_size,
                              hipStream_t stream)
{
    (void)in_sizes; (void)n_in; (void)out_size;
    const float* x  = (const float*)d_in[0];
    const float* s0 = (const float*)d_in[1];
    const float* wh = (const float*)d_in[2];
    const float* wt = (const float*)d_in[3];
    const float* wc = (const float*)d_in[4];
    const float* Rh = (const float*)d_in[5];
    const float* Rt = (const float*)d_in[6];
    const float* Rc = (const float*)d_in[7];
    const float* bh = (const float*)d_in[8];
    const float* bt = (const float*)d_in[9];
    const float* bc = (const float*)d_in[10];

    float* out = (float*)d_out;
    float* sT  = out + (size_t)Bb * Tt * Hh;

    const size_t THB   = (size_t)Tt * Hh * Bb;
    const size_t p2f   = 3 * THB * 4, p2h = 3 * THB * 2;
    const size_t ringS = (size_t)NS * SLOT_E * 4;   // 2 MB
    const size_t shF   = THB * 4;                   // 128 MB

    char* w = (char*)d_ws;

    if (ws_size >= p2f + ringS + shF + 4096) {
        // tier A: fp32 P2
        float* P2 = (float*)w;
        float* ring = (float*)(w + p2f);
        float* shist = (float*)(w + p2f + ringS);
        proj_gemm<float><<<dim3(16, 512), 256, 0, stream>>>(x, wh, wt, wc, P2);
        init_ring_s<<<128, 256, 0, stream>>>(s0, ring);
        launch_recur<float>(Rh, Rt, Rc, bh, bt, bc, P2, ring, shist, s0, stream);
        out_transpose_hist<<<dim3(8, 1024), 256, 0, stream>>>(shist, out, sT);
    } else {
        // tier B: bf16 P2 (ring + shist stay fp32)
        __hip_bfloat16* P2 = (__hip_bfloat16*)w;
        float* ring = (float*)(w + p2h);
        float* shist = (float*)(w + p2h + ringS);
        proj_gemm<__hip_bfloat16><<<dim3(16, 512), 256, 0, stream>>>(x, wh, wt, wc, P2);
        init_ring_s<<<128, 256, 0, stream>>>(s0, ring);
        launch_recur<__hip_bfloat16>(Rh, Rt, Rc, bh, bt, bc, P2, ring, shist, s0, stream);
        out_transpose_hist<<<dim3(8, 1024), 256, 0, stream>>>(shist, out, sT);
    }
}